// Round 2
// baseline (140477.576 us; speedup 1.0000x reference)
//
#include <hip/hip_runtime.h>
#include <math.h>

#define S_LEN 131072
#define H 100
#define G 400   // 4*H

typedef float v2f __attribute__((ext_vector_type(2)));
typedef float v4f __attribute__((ext_vector_type(4)));

__device__ __forceinline__ float sigmoid_fast(float x) {
    return 1.0f / (1.0f + __expf(-x));
}
__device__ __forceinline__ float tanh_fast(float x) {
    // 2*sigmoid(2x) - 1 ; saturates correctly for large |x|
    return 2.0f / (1.0f + __expf(-2.0f * x)) - 1.0f;
}

// 448 threads = 7 waves. Second launch_bounds arg = 2 waves/EU minimum:
// caps VGPRs at 256 so the 100-float weight row stays IN REGISTERS.
// (Round-1 lesson: default heuristic targeted 8 waves/EU -> 64 VGPRs -> the
// whole w[] array spilled to scratch; 1560 cycles/step instead of ~550.)
__global__ __launch_bounds__(448, 2) void lstm_seq_kernel(
    const float* __restrict__ x,      // [S]
    const float* __restrict__ W_ih,   // [400]  (400x1)
    const float* __restrict__ W_hh,   // [400,100] row-major
    const float* __restrict__ b_ih,   // [400]
    const float* __restrict__ b_hh,   // [400]
    const float* __restrict__ W_out,  // [100]  (1x100)
    const float* __restrict__ b_out,  // [1]
    float* __restrict__ out)          // [1]
{
    __shared__ __align__(16) float h_lds[112];       // hidden state (100 used)
    __shared__ __align__(16) float act_lds[4][112];  // activated gates i,f,g,o

    const int t = threadIdx.x;

    // ---- load this thread's W_hh row into registers (t < 400) ----
    v2f w[50];
    float wih = 0.0f, bsum = 0.0f;
    if (t < G) {
        #pragma unroll
        for (int j = 0; j < 50; ++j) {
            w[j].x = W_hh[t * H + 2 * j];
            w[j].y = W_hh[t * H + 2 * j + 1];
        }
        wih  = W_ih[t];
        bsum = b_ih[t] + b_hh[t];
    }

    float c = 0.0f;                    // cell state, owned by threads 0..99
    if (t < H) h_lds[t] = 0.0f;
    __syncthreads();

    const int gidx = t / H;            // which gate block: 0=i 1=f 2=g 3=o

    float xv_next = x[0];              // software-pipelined input load

    for (int step = 0; step < S_LEN; ++step) {
        float xv = xv_next;
        if (step + 1 < S_LEN) xv_next = x[step + 1];  // issue early; ~200cy
                                                       // latency hides under matvec

        // ---- matvec: gate_r = W_hh[r,:] @ h + x*W_ih[r] + b ----
        v2f acc[4];
        acc[0] = (v2f){0.0f, 0.0f};
        acc[1] = (v2f){0.0f, 0.0f};
        acc[2] = (v2f){0.0f, 0.0f};
        acc[3] = (v2f){0.0f, 0.0f};
        if (t < G) {
            #pragma unroll
            for (int j = 0; j < 25; ++j) {
                v4f h4 = *(const v4f*)&h_lds[4 * j];   // LDS broadcast read
                v2f hlo = {h4.x, h4.y};
                v2f hhi = {h4.z, h4.w};
                // 4 independent chains (depth ~12) -> FMA latency fully hidden
                acc[(2 * j) & 3]     = __builtin_elementwise_fma(w[2 * j],     hlo, acc[(2 * j) & 3]);
                acc[(2 * j + 1) & 3] = __builtin_elementwise_fma(w[2 * j + 1], hhi, acc[(2 * j + 1) & 3]);
            }
            v2f s01 = acc[0] + acc[1];
            v2f s23 = acc[2] + acc[3];
            float gate = (s01.x + s01.y) + (s23.x + s23.y)
                       + xv * wih + bsum;
            // activate in the parallel phase (distributes the transcendentals)
            float a = (gidx == 2) ? tanh_fast(gate) : sigmoid_fast(gate);
            act_lds[gidx][t - gidx * H] = a;
        }
        __syncthreads();               // gates ready

        if (t < H) {
            float ig = act_lds[0][t];
            float fg = act_lds[1][t];
            float gg = act_lds[2][t];
            float og = act_lds[3][t];
            c = fg * c + ig * gg;
            h_lds[t] = og * tanh_fast(c);
        }
        __syncthreads();               // h ready for next step
    }

    if (t == 0) {
        float s = b_out[0];
        #pragma unroll 4
        for (int j = 0; j < H; ++j) s += W_out[j] * h_lds[j];
        out[0] = s;
    }
}

extern "C" void kernel_launch(void* const* d_in, const int* in_sizes, int n_in,
                              void* d_out, int out_size, void* d_ws, size_t ws_size,
                              hipStream_t stream) {
    const float* x     = (const float*)d_in[0];
    const float* W_ih  = (const float*)d_in[1];
    const float* W_hh  = (const float*)d_in[2];
    const float* b_ih  = (const float*)d_in[3];
    const float* b_hh  = (const float*)d_in[4];
    const float* W_out = (const float*)d_in[5];
    const float* b_out = (const float*)d_in[6];
    float* out = (float*)d_out;

    lstm_seq_kernel<<<1, 448, 0, stream>>>(x, W_ih, W_hh, b_ih, b_hh,
                                           W_out, b_out, out);
}

// Round 3
// 98410.968 us; speedup vs baseline: 1.4275x; 1.4275x over previous
//
#include <hip/hip_runtime.h>
#include <math.h>

#define S_LEN 131072
#define H 100
#define G 400   // 4*H

typedef float v4f __attribute__((ext_vector_type(4)));

__device__ __forceinline__ float sigmoid_fast(float x) {
    return 1.0f / (1.0f + __expf(-x));
}
__device__ __forceinline__ float tanh_fast(float x) {
    // 2*sigmoid(2x) - 1 ; saturates correctly for large |x|
    return 2.0f / (1.0f + __expf(-2.0f * x)) - 1.0f;
}

// Round-2 lesson (guide rule #20): runtime-indexed ext_vector arrays (w[2*j],
// acc[(2*j)&3]) go to SCRATCH — SROA runs before unrolling. VGPR_Count=64 +
// 231MB scratch write-back proved it. Fix: NAMED registers, straight-line code.
__global__ __launch_bounds__(448, 2) void lstm_seq_kernel(
    const float* __restrict__ x,      // [S]
    const float* __restrict__ W_ih,   // [400]  (400x1)
    const float* __restrict__ W_hh,   // [400,100] row-major
    const float* __restrict__ b_ih,   // [400]
    const float* __restrict__ b_hh,   // [400]
    const float* __restrict__ W_out,  // [100]  (1x100)
    const float* __restrict__ b_out,  // [1]
    float* __restrict__ out)          // [1]
{
    __shared__ __align__(16) float h_lds[112];       // hidden state (100 used)
    __shared__ __align__(16) float act_lds[4][112];  // activated gates i,f,g,o

    const int t = threadIdx.x;
    const bool worker = (t < G);
    const int gidx = t / H;            // gate block 0..3 (workers only)

    // ---- 25 NAMED v4f weight registers: W_hh row t (100 floats) ----
    v4f w0, w1, w2, w3, w4, w5, w6, w7, w8, w9, w10, w11, w12,
        w13, w14, w15, w16, w17, w18, w19, w20, w21, w22, w23, w24;
    float wih = 0.0f, bsum = 0.0f;
    float* act_slot = &act_lds[0][0];  // this thread's gate output slot
    if (worker) {
        const float* wr = W_hh + t * H;   // row base: 400*t bytes -> 16B aligned
#define LOADW(i) w##i = *(const v4f*)(wr + 4 * (i))
        LOADW(0);  LOADW(1);  LOADW(2);  LOADW(3);  LOADW(4);
        LOADW(5);  LOADW(6);  LOADW(7);  LOADW(8);  LOADW(9);
        LOADW(10); LOADW(11); LOADW(12); LOADW(13); LOADW(14);
        LOADW(15); LOADW(16); LOADW(17); LOADW(18); LOADW(19);
        LOADW(20); LOADW(21); LOADW(22); LOADW(23); LOADW(24);
#undef LOADW
        wih  = W_ih[t];
        bsum = b_ih[t] + b_hh[t];
        act_slot = &act_lds[gidx][t - gidx * H];
    }

    float c = 0.0f;                    // cell state, owned by threads 0..99
    if (t < H) h_lds[t] = 0.0f;
    __syncthreads();

    const v4f* hv = (const v4f*)h_lds;

    float xv_next = x[0];              // software-pipelined uniform input load

    for (int step = 0; step < S_LEN; ++step) {
        float xv = xv_next;
        int nxt = (step + 1 < S_LEN) ? (step + 1) : step;
        xv_next = x[nxt];              // issue early; latency hides under matvec

        if (worker) {
            // ---- matvec: gate_t = W_hh[t,:] @ h  (4 named acc chains) ----
            v4f a0 = {0.f,0.f,0.f,0.f}, a1 = {0.f,0.f,0.f,0.f},
                a2 = {0.f,0.f,0.f,0.f}, a3 = {0.f,0.f,0.f,0.f};
#define FMA4(i, acc) acc = __builtin_elementwise_fma(w##i, hv[i], acc)
            FMA4(0,  a0); FMA4(1,  a1); FMA4(2,  a2); FMA4(3,  a3);
            FMA4(4,  a0); FMA4(5,  a1); FMA4(6,  a2); FMA4(7,  a3);
            FMA4(8,  a0); FMA4(9,  a1); FMA4(10, a2); FMA4(11, a3);
            FMA4(12, a0); FMA4(13, a1); FMA4(14, a2); FMA4(15, a3);
            FMA4(16, a0); FMA4(17, a1); FMA4(18, a2); FMA4(19, a3);
            FMA4(20, a0); FMA4(21, a1); FMA4(22, a2); FMA4(23, a3);
            FMA4(24, a0);
#undef FMA4
            v4f s = (a0 + a1) + (a2 + a3);
            float gate = (s.x + s.y) + (s.z + s.w)
                       + __builtin_fmaf(xv, wih, bsum);
            // activate in the parallel phase (distributes the transcendentals)
            float a = (gidx == 2) ? tanh_fast(gate) : sigmoid_fast(gate);
            *act_slot = a;
        }
        __syncthreads();               // gates ready

        if (t < H) {
            float ig = act_lds[0][t];
            float fg = act_lds[1][t];
            float gg = act_lds[2][t];
            float og = act_lds[3][t];
            c = fg * c + ig * gg;
            h_lds[t] = og * tanh_fast(c);
        }
        __syncthreads();               // h ready for next step
    }

    if (t == 0) {
        float s = b_out[0];
        #pragma unroll 4
        for (int j = 0; j < H; ++j) s += W_out[j] * h_lds[j];
        out[0] = s;
    }
}

extern "C" void kernel_launch(void* const* d_in, const int* in_sizes, int n_in,
                              void* d_out, int out_size, void* d_ws, size_t ws_size,
                              hipStream_t stream) {
    const float* x     = (const float*)d_in[0];
    const float* W_ih  = (const float*)d_in[1];
    const float* W_hh  = (const float*)d_in[2];
    const float* b_ih  = (const float*)d_in[3];
    const float* b_hh  = (const float*)d_in[4];
    const float* W_out = (const float*)d_in[5];
    const float* b_out = (const float*)d_in[6];
    float* out = (float*)d_out;

    lstm_seq_kernel<<<1, 448, 0, stream>>>(x, W_ih, W_hh, b_ih, b_hh,
                                           W_out, b_out, out);
}